// Round 2
// 420.714 us; speedup vs baseline: 1.0445x; 1.0445x over previous
//
#include <hip/hip_runtime.h>
#include <math.h>

#define B_DIM 256
#define K_DIM 256
#define H_DIM 1024
#define SEQ_DIM 128
#define L_DIM 3
#define NSPLIT 16
#define BS (B_DIM / NSPLIT)     // 16 b's per flash wave
#define SK 8                    // split-K for the H x H gemm

typedef float vfloat4 __attribute__((ext_vector_type(4)));

__device__ __forceinline__ float4 ntload4(const float* p) {
    vfloat4 v = __builtin_nontemporal_load((const vfloat4*)p);
    return make_float4(v.x, v.y, v.z, v.w);
}

// ---------------- kernel 1: single-wave flash online softmax-weighted sum ----------------
// grid (K, NSPLIT), block 64 (ONE wave). Each wave: k fixed, iterates BS b's.
// NSPLIT=16 -> 4096 waves = 4 waves/SIMD for latency hiding (was 2).
// No LDS, no __syncthreads: score reduce is 6 shfl_xor butterflies.
// Lane owns 16 strided floats: h = r*256 + lane*4 + {0..3}, r = 0..3.
__global__ __launch_bounds__(64, 4) void k_flash(const float* __restrict__ ent,
                                                 const float* __restrict__ S,
                                                 float* __restrict__ num,
                                                 float* __restrict__ ml) {
    int k = blockIdx.x, sp = blockIdx.y, lane = threadIdx.x;
    int b0 = sp * BS;

    const float* Sp = S   + ((size_t)(b0 * K_DIM + k)) * H_DIM;
    const float* Xp = ent + (size_t)b0 * SEQ_DIM * H_DIM;

    float4 acc[4] = {{0,0,0,0},{0,0,0,0},{0,0,0,0},{0,0,0,0}};
    float m = -INFINITY, l = 0.f;

    float4 sc[4], xc[4];
#pragma unroll
    for (int r = 0; r < 4; ++r) {
        int idx = r * 256 + lane * 4;
        sc[r] = ntload4(Sp + idx);              // S is single-use: nontemporal
        xc[r] = *(const float4*)(Xp + idx);     // x rows are reused across k-blocks: cache
    }

    for (int bb = 0; bb < BS; ++bb) {
        float4 sn[4] = {{0,0,0,0},{0,0,0,0},{0,0,0,0},{0,0,0,0}};
        float4 xn[4] = {{0,0,0,0},{0,0,0,0},{0,0,0,0},{0,0,0,0}};
        if (bb + 1 < BS) {
            const float* Snp = Sp + (size_t)(bb + 1) * K_DIM * H_DIM;
            const float* Xnp = Xp + (size_t)(bb + 1) * SEQ_DIM * H_DIM;
#pragma unroll
            for (int r = 0; r < 4; ++r) {
                int idx = r * 256 + lane * 4;
                sn[r] = ntload4(Snp + idx);
                xn[r] = *(const float4*)(Xnp + idx);
            }
        }
        float partial = 0.f;
#pragma unroll
        for (int r = 0; r < 4; ++r)
            partial += sc[r].x * xc[r].x + sc[r].y * xc[r].y
                     + sc[r].z * xc[r].z + sc[r].w * xc[r].w;
#pragma unroll
        for (int off = 1; off < 64; off <<= 1)
            partial += __shfl_xor(partial, off, 64);
        float s = partial;                       // full dot, all lanes

        float mn = fmaxf(m, s);
        float scale = expf(m - mn);              // first iter: expf(-inf)=0
        float e = expf(s - mn);
#pragma unroll
        for (int r = 0; r < 4; ++r) {
            acc[r].x = acc[r].x * scale + e * sc[r].x;
            acc[r].y = acc[r].y * scale + e * sc[r].y;
            acc[r].z = acc[r].z * scale + e * sc[r].z;
            acc[r].w = acc[r].w * scale + e * sc[r].w;
        }
        l = l * scale + e;
        m = mn;
#pragma unroll
        for (int r = 0; r < 4; ++r) { sc[r] = sn[r]; xc[r] = xn[r]; }
    }

    float* np = num + ((size_t)(sp * K_DIM + k)) * H_DIM;
#pragma unroll
    for (int r = 0; r < 4; ++r)
        *(float4*)(np + r * 256 + lane * 4) = acc[r];
    if (lane == 0) {
        ml[sp * K_DIM + k] = m;
        ml[NSPLIT * K_DIM + sp * K_DIM + k] = l;
    }
}

// ---------------- kernel 2: merge the NSPLIT online-softmax partials ----------------
__global__ void k_combine(const float* __restrict__ num, const float* __restrict__ ml,
                          float* __restrict__ u) {
    int k = blockIdx.x, t = threadIdx.x;
    float M = -INFINITY;
#pragma unroll
    for (int sp = 0; sp < NSPLIT; ++sp) M = fmaxf(M, ml[sp * K_DIM + k]);
    float w[NSPLIT];
    float denom = 0.f;
#pragma unroll
    for (int sp = 0; sp < NSPLIT; ++sp) {
        w[sp] = expf(ml[sp * K_DIM + k] - M);
        denom += w[sp] * ml[NSPLIT * K_DIM + sp * K_DIM + k];
    }
    float inv = 1.f / denom;
    float4 a = {0.f, 0.f, 0.f, 0.f};
#pragma unroll
    for (int sp = 0; sp < NSPLIT; ++sp) {
        float4 n4 = ntload4(num + ((size_t)(sp * K_DIM + k)) * H_DIM + t * 4);
        a.x += w[sp] * n4.x; a.y += w[sp] * n4.y; a.z += w[sp] * n4.z; a.w += w[sp] * n4.w;
    }
    a.x *= inv; a.y *= inv; a.z *= inv; a.w *= inv;
    *(float4*)(u + (size_t)k * H_DIM + t * 4) = a;
}

// ---------------- kernel 3: split-K vector GEMM, vpart[z][b][h] = U[b, ks] @ Hw[h, ks]^T ----
// k-major LDS tiles (Us[kk][b], Hs[kk][h], pad 68) so the inner loop reads
// both fragments as ds_read_b128 (2-way bank aliasing = free) instead of
// 8 scalar stride-17 column walks. SK=8 -> 512 blocks = 2 blocks/CU.
__global__ __launch_bounds__(256, 2) void k_vgemm(const float* __restrict__ u,
                                                  const float* __restrict__ Hw,
                                                  float* __restrict__ vpart) {
    __shared__ float Us[16][68];
    __shared__ float Hs[16][68];
    int tid = threadIdx.x;
    int tx = tid & 15, ty = tid >> 4;
    int hx = blockIdx.x * 64, by = blockIdx.y * 64, z = blockIdx.z;
    float acc[4][4] = {};
    int r = tid >> 2, cc = (tid & 3) * 4;       // load mapping: row r (0..63), 4 cols at cc
    int k0 = z * (H_DIM / SK);                  // 128 k's per z
    for (int kt = 0; kt < H_DIM / SK; kt += 16) {
        int kk0 = k0 + kt;
        float4 uv = *(const float4*)(u  + (size_t)(by + r) * H_DIM + kk0 + cc);
        float4 hv = *(const float4*)(Hw + (size_t)(hx + r) * H_DIM + kk0 + cc);
        // transpose into k-major LDS (store banks: 2-way, free)
        Us[cc + 0][r] = uv.x; Us[cc + 1][r] = uv.y; Us[cc + 2][r] = uv.z; Us[cc + 3][r] = uv.w;
        Hs[cc + 0][r] = hv.x; Hs[cc + 1][r] = hv.y; Hs[cc + 2][r] = hv.z; Hs[cc + 3][r] = hv.w;
        __syncthreads();
#pragma unroll
        for (int kk = 0; kk < 16; ++kk) {
            float4 av = *(const float4*)&Us[kk][ty * 4];   // b-fragment, ds_read_b128
            float4 bv = *(const float4*)&Hs[kk][tx * 4];   // h-fragment, ds_read_b128
            acc[0][0] += av.x * bv.x; acc[0][1] += av.x * bv.y; acc[0][2] += av.x * bv.z; acc[0][3] += av.x * bv.w;
            acc[1][0] += av.y * bv.x; acc[1][1] += av.y * bv.y; acc[1][2] += av.y * bv.z; acc[1][3] += av.y * bv.w;
            acc[2][0] += av.z * bv.x; acc[2][1] += av.z * bv.y; acc[2][2] += av.z * bv.z; acc[2][3] += av.z * bv.w;
            acc[3][0] += av.w * bv.x; acc[3][1] += av.w * bv.y; acc[3][2] += av.w * bv.z; acc[3][3] += av.w * bv.w;
        }
        __syncthreads();
    }
#pragma unroll
    for (int i = 0; i < 4; ++i) {
        int b = by + ty * 4 + i;
        float4 o = {acc[i][0], acc[i][1], acc[i][2], acc[i][3]};
        *(float4*)(vpart + ((size_t)z * B_DIM + b) * H_DIM + hx + tx * 4) = o;
    }
}

// ---------------- kernel 4: split-K reduce + x add + PReLU + R_w projection ----------------
__global__ void k_final(const float* __restrict__ vpart, const float* __restrict__ ent,
                        const float* __restrict__ alpha, const float* __restrict__ Rw,
                        float* __restrict__ out) {
    __shared__ float sm[4 * L_DIM];
    int b = blockIdx.x, t = threadIdx.x;
    int lane = t & 63, wave = t >> 6;
    float4 v = *(const float4*)(ent + (size_t)b * SEQ_DIM * H_DIM + t * 4);
#pragma unroll
    for (int z = 0; z < SK; ++z) {
        float4 p4 = *(const float4*)(vpart + ((size_t)z * B_DIM + b) * H_DIM + t * 4);
        v.x += p4.x; v.y += p4.y; v.z += p4.z; v.w += p4.w;
    }
    float4 al = *(const float4*)(alpha + t * 4);
    v.x = (v.x >= 0.f) ? v.x : al.x * v.x;
    v.y = (v.y >= 0.f) ? v.y : al.y * v.y;
    v.z = (v.z >= 0.f) ? v.z : al.z * v.z;
    v.w = (v.w >= 0.f) ? v.w : al.w * v.w;
    float p[L_DIM];
#pragma unroll
    for (int l = 0; l < L_DIM; ++l) {
        float4 r4 = *(const float4*)(Rw + l * H_DIM + t * 4);
        p[l] = v.x * r4.x + v.y * r4.y + v.z * r4.z + v.w * r4.w;
    }
#pragma unroll
    for (int off = 32; off > 0; off >>= 1) {
#pragma unroll
        for (int l = 0; l < L_DIM; ++l) p[l] += __shfl_down(p[l], off, 64);
    }
    if (lane == 0) {
#pragma unroll
        for (int l = 0; l < L_DIM; ++l) sm[wave * L_DIM + l] = p[l];
    }
    __syncthreads();
    if (t < L_DIM) {
        out[b * L_DIM + t] = sm[t] + sm[L_DIM + t] + sm[2 * L_DIM + t] + sm[3 * L_DIM + t];
    }
}

extern "C" void kernel_launch(void* const* d_in, const int* in_sizes, int n_in,
                              void* d_out, int out_size, void* d_ws, size_t ws_size,
                              hipStream_t stream) {
    const float* ent   = (const float*)d_in[0];   // (256,128,1024)
    const float* S     = (const float*)d_in[1];   // (256, 256*1024)
    const float* Hw    = (const float*)d_in[2];   // (1024,1024)
    const float* Rw    = (const float*)d_in[3];   // (3,1024)
    const float* alpha = (const float*)d_in[4];   // (1024,)
    float* out = (float*)d_out;                   // (256,3)

    float* ws    = (float*)d_ws;
    float* num   = ws;                                        // NSPLIT*K*H = 4M floats (16 MB)
    float* ml    = num + (size_t)NSPLIT * K_DIM * H_DIM;      // 2*NSPLIT*K
    float* u     = ml + 2 * NSPLIT * K_DIM;                   // K*H (1 MB)
    float* vpart = u + (size_t)K_DIM * H_DIM;                 // SK*B*H (8 MB)
    // total ~26 MB

    k_flash  <<<dim3(K_DIM, NSPLIT), 64, 0, stream>>>(ent, S, num, ml);
    k_combine<<<K_DIM, 256, 0, stream>>>(num, ml, u);
    k_vgemm  <<<dim3(H_DIM / 64, B_DIM / 64, SK), 256, 0, stream>>>(u, Hw, vpart);
    k_final  <<<B_DIM, 256, 0, stream>>>(vpart, ent, alpha, Rw, out);
}

// Round 3
// 407.550 us; speedup vs baseline: 1.0782x; 1.0323x over previous
//
#include <hip/hip_runtime.h>
#include <math.h>

#define B_DIM 256
#define K_DIM 256
#define H_DIM 1024
#define SEQ_DIM 128
#define L_DIM 3
#define NSPLIT 8
#define BS (B_DIM / NSPLIT)     // 32 b's per flash wave
#define KW 4                    // k-waves per flash block (share sp, consecutive k)
#define SK 8                    // split-K for the H x H gemm

typedef float vfloat4 __attribute__((ext_vector_type(4)));

__device__ __forceinline__ float4 ntload4(const float* p) {
    vfloat4 v = __builtin_nontemporal_load((const vfloat4*)p);
    return make_float4(v.x, v.y, v.z, v.w);
}

// ---------------- kernel 1: flash online softmax-weighted sum ----------------
// grid (K/KW, NSPLIT), block 256 = 4 waves. All 4 waves share sp (same x rows ->
// L1 hits) and take consecutive k's (4 consecutive 4KB S rows per b-step ->
// 16KB contiguous DRAM bursts). Each wave: k fixed, iterates BS b's.
// Score reduce: 6 shfl_xor butterflies, no LDS, no __syncthreads.
// Lane owns 16 strided floats: h = r*256 + lane*4 + {0..3}, r = 0..3.
__global__ __launch_bounds__(256, 2) void k_flash(const float* __restrict__ ent,
                                                  const float* __restrict__ S,
                                                  float* __restrict__ num,
                                                  float* __restrict__ ml) {
    int tid = threadIdx.x;
    int wave = tid >> 6, lane = tid & 63;
    int k = blockIdx.x * KW + wave;
    int sp = blockIdx.y;
    int b0 = sp * BS;

    const float* Sp = S   + ((size_t)(b0 * K_DIM + k)) * H_DIM;
    const float* Xp = ent + (size_t)b0 * SEQ_DIM * H_DIM;

    float4 acc[4] = {{0,0,0,0},{0,0,0,0},{0,0,0,0},{0,0,0,0}};
    float m = -INFINITY, l = 0.f;

    float4 sc[4], xc[4];
#pragma unroll
    for (int r = 0; r < 4; ++r) {
        int idx = r * 256 + lane * 4;
        sc[r] = ntload4(Sp + idx);              // S is single-use: nontemporal
        xc[r] = *(const float4*)(Xp + idx);     // x rows reused by all k-waves: cache
    }

    for (int bb = 0; bb < BS; ++bb) {
        float4 sn[4] = {{0,0,0,0},{0,0,0,0},{0,0,0,0},{0,0,0,0}};
        float4 xn[4] = {{0,0,0,0},{0,0,0,0},{0,0,0,0},{0,0,0,0}};
        if (bb + 1 < BS) {
            const float* Snp = Sp + (size_t)(bb + 1) * K_DIM * H_DIM;
            const float* Xnp = Xp + (size_t)(bb + 1) * SEQ_DIM * H_DIM;
#pragma unroll
            for (int r = 0; r < 4; ++r) {
                int idx = r * 256 + lane * 4;
                sn[r] = ntload4(Snp + idx);
                xn[r] = *(const float4*)(Xnp + idx);
            }
        }
        float partial = 0.f;
#pragma unroll
        for (int r = 0; r < 4; ++r)
            partial += sc[r].x * xc[r].x + sc[r].y * xc[r].y
                     + sc[r].z * xc[r].z + sc[r].w * xc[r].w;
#pragma unroll
        for (int off = 1; off < 64; off <<= 1)
            partial += __shfl_xor(partial, off, 64);
        float s = partial;                       // full dot, all lanes

        float mn = fmaxf(m, s);
        float scale = expf(m - mn);              // first iter: expf(-inf)=0
        float e = expf(s - mn);
#pragma unroll
        for (int r = 0; r < 4; ++r) {
            acc[r].x = acc[r].x * scale + e * sc[r].x;
            acc[r].y = acc[r].y * scale + e * sc[r].y;
            acc[r].z = acc[r].z * scale + e * sc[r].z;
            acc[r].w = acc[r].w * scale + e * sc[r].w;
        }
        l = l * scale + e;
        m = mn;
#pragma unroll
        for (int r = 0; r < 4; ++r) { sc[r] = sn[r]; xc[r] = xn[r]; }
    }

    float* np = num + ((size_t)(sp * K_DIM + k)) * H_DIM;
#pragma unroll
    for (int r = 0; r < 4; ++r)
        *(float4*)(np + r * 256 + lane * 4) = acc[r];
    if (lane == 0) {
        ml[sp * K_DIM + k] = m;
        ml[NSPLIT * K_DIM + sp * K_DIM + k] = l;
    }
}

// ---------------- kernel 2: merge the NSPLIT online-softmax partials ----------------
__global__ void k_combine(const float* __restrict__ num, const float* __restrict__ ml,
                          float* __restrict__ u) {
    int k = blockIdx.x, t = threadIdx.x;
    float M = -INFINITY;
#pragma unroll
    for (int sp = 0; sp < NSPLIT; ++sp) M = fmaxf(M, ml[sp * K_DIM + k]);
    float w[NSPLIT];
    float denom = 0.f;
#pragma unroll
    for (int sp = 0; sp < NSPLIT; ++sp) {
        w[sp] = expf(ml[sp * K_DIM + k] - M);
        denom += w[sp] * ml[NSPLIT * K_DIM + sp * K_DIM + k];
    }
    float inv = 1.f / denom;
    float4 a = {0.f, 0.f, 0.f, 0.f};
#pragma unroll
    for (int sp = 0; sp < NSPLIT; ++sp) {
        float4 n4 = ntload4(num + ((size_t)(sp * K_DIM + k)) * H_DIM + t * 4);
        a.x += w[sp] * n4.x; a.y += w[sp] * n4.y; a.z += w[sp] * n4.z; a.w += w[sp] * n4.w;
    }
    a.x *= inv; a.y *= inv; a.z *= inv; a.w *= inv;
    *(float4*)(u + (size_t)k * H_DIM + t * 4) = a;
}

// ---------------- kernel 3: split-K vector GEMM, vpart[z][b][h] = U[b, ks] @ Hw[h, ks]^T ----
// k-major LDS tiles (Us[kk][b], Hs[kk][h], pad 68) so the inner loop reads
// both fragments as ds_read_b128 (2-way bank aliasing = free). SK=8 -> 512
// blocks = 2 blocks/CU.
__global__ __launch_bounds__(256, 2) void k_vgemm(const float* __restrict__ u,
                                                  const float* __restrict__ Hw,
                                                  float* __restrict__ vpart) {
    __shared__ float Us[16][68];
    __shared__ float Hs[16][68];
    int tid = threadIdx.x;
    int tx = tid & 15, ty = tid >> 4;
    int hx = blockIdx.x * 64, by = blockIdx.y * 64, z = blockIdx.z;
    float acc[4][4] = {};
    int r = tid >> 2, cc = (tid & 3) * 4;       // load mapping: row r (0..63), 4 cols at cc
    int k0 = z * (H_DIM / SK);                  // 128 k's per z
    for (int kt = 0; kt < H_DIM / SK; kt += 16) {
        int kk0 = k0 + kt;
        float4 uv = *(const float4*)(u  + (size_t)(by + r) * H_DIM + kk0 + cc);
        float4 hv = *(const float4*)(Hw + (size_t)(hx + r) * H_DIM + kk0 + cc);
        // transpose into k-major LDS (store banks: 2-way, free)
        Us[cc + 0][r] = uv.x; Us[cc + 1][r] = uv.y; Us[cc + 2][r] = uv.z; Us[cc + 3][r] = uv.w;
        Hs[cc + 0][r] = hv.x; Hs[cc + 1][r] = hv.y; Hs[cc + 2][r] = hv.z; Hs[cc + 3][r] = hv.w;
        __syncthreads();
#pragma unroll
        for (int kk = 0; kk < 16; ++kk) {
            float4 av = *(const float4*)&Us[kk][ty * 4];   // b-fragment, broadcast-ish
            float4 bv = *(const float4*)&Hs[kk][tx * 4];   // h-fragment, ds_read_b128
            acc[0][0] += av.x * bv.x; acc[0][1] += av.x * bv.y; acc[0][2] += av.x * bv.z; acc[0][3] += av.x * bv.w;
            acc[1][0] += av.y * bv.x; acc[1][1] += av.y * bv.y; acc[1][2] += av.y * bv.z; acc[1][3] += av.y * bv.w;
            acc[2][0] += av.z * bv.x; acc[2][1] += av.z * bv.y; acc[2][2] += av.z * bv.z; acc[2][3] += av.z * bv.w;
            acc[3][0] += av.w * bv.x; acc[3][1] += av.w * bv.y; acc[3][2] += av.w * bv.z; acc[3][3] += av.w * bv.w;
        }
        __syncthreads();
    }
#pragma unroll
    for (int i = 0; i < 4; ++i) {
        int b = by + ty * 4 + i;
        float4 o = {acc[i][0], acc[i][1], acc[i][2], acc[i][3]};
        *(float4*)(vpart + ((size_t)z * B_DIM + b) * H_DIM + hx + tx * 4) = o;
    }
}

// ---------------- kernel 4: split-K reduce + x add + PReLU + R_w projection ----------------
__global__ void k_final(const float* __restrict__ vpart, const float* __restrict__ ent,
                        const float* __restrict__ alpha, const float* __restrict__ Rw,
                        float* __restrict__ out) {
    __shared__ float sm[4 * L_DIM];
    int b = blockIdx.x, t = threadIdx.x;
    int lane = t & 63, wave = t >> 6;
    float4 v = *(const float4*)(ent + (size_t)b * SEQ_DIM * H_DIM + t * 4);
#pragma unroll
    for (int z = 0; z < SK; ++z) {
        float4 p4 = *(const float4*)(vpart + ((size_t)z * B_DIM + b) * H_DIM + t * 4);
        v.x += p4.x; v.y += p4.y; v.z += p4.z; v.w += p4.w;
    }
    float4 al = *(const float4*)(alpha + t * 4);
    v.x = (v.x >= 0.f) ? v.x : al.x * v.x;
    v.y = (v.y >= 0.f) ? v.y : al.y * v.y;
    v.z = (v.z >= 0.f) ? v.z : al.z * v.z;
    v.w = (v.w >= 0.f) ? v.w : al.w * v.w;
    float p[L_DIM];
#pragma unroll
    for (int l = 0; l < L_DIM; ++l) {
        float4 r4 = *(const float4*)(Rw + l * H_DIM + t * 4);
        p[l] = v.x * r4.x + v.y * r4.y + v.z * r4.z + v.w * r4.w;
    }
#pragma unroll
    for (int off = 32; off > 0; off >>= 1) {
#pragma unroll
        for (int l = 0; l < L_DIM; ++l) p[l] += __shfl_down(p[l], off, 64);
    }
    if (lane == 0) {
#pragma unroll
        for (int l = 0; l < L_DIM; ++l) sm[wave * L_DIM + l] = p[l];
    }
    __syncthreads();
    if (t < L_DIM) {
        out[b * L_DIM + t] = sm[t] + sm[L_DIM + t] + sm[2 * L_DIM + t] + sm[3 * L_DIM + t];
    }
}

extern "C" void kernel_launch(void* const* d_in, const int* in_sizes, int n_in,
                              void* d_out, int out_size, void* d_ws, size_t ws_size,
                              hipStream_t stream) {
    const float* ent   = (const float*)d_in[0];   // (256,128,1024)
    const float* S     = (const float*)d_in[1];   // (256, 256*1024)
    const float* Hw    = (const float*)d_in[2];   // (1024,1024)
    const float* Rw    = (const float*)d_in[3];   // (3,1024)
    const float* alpha = (const float*)d_in[4];   // (1024,)
    float* out = (float*)d_out;                   // (256,3)

    float* ws    = (float*)d_ws;
    float* num   = ws;                                        // NSPLIT*K*H = 2M floats (8 MB)
    float* ml    = num + (size_t)NSPLIT * K_DIM * H_DIM;      // 2*NSPLIT*K
    float* u     = ml + 2 * NSPLIT * K_DIM;                   // K*H (1 MB)
    float* vpart = u + (size_t)K_DIM * H_DIM;                 // SK*B*H (8 MB)
    // total ~17 MB

    k_flash  <<<dim3(K_DIM / KW, NSPLIT), 256, 0, stream>>>(ent, S, num, ml);
    k_combine<<<K_DIM, 256, 0, stream>>>(num, ml, u);
    k_vgemm  <<<dim3(H_DIM / 64, B_DIM / 64, SK), 256, 0, stream>>>(u, Hw, vpart);
    k_final  <<<B_DIM, 256, 0, stream>>>(vpart, ent, alpha, Rw, out);
}